// Round 1
// baseline (31.270 us; speedup 1.0000x reference)
//
#include <hip/hip_runtime.h>

#define NPTS 512
#define DIM  128
#define EPSF 1e-16f

// One block per anchor i. 256 threads.
// Phase 1: compute distance row d_i[j] for all j into LDS (reference semantics:
//   draw = relu(n_i + n_j - 2*dot); dist = draw==0 ? EPS : sqrt(draw+EPS)+EPS).
// Phase 2: positives list (same label, j!=i), deterministic order via sort.
// Phase 3: accumulate sum(relu(d_ij - d_ik + b)) and count(loss > 1e-16)
//          over negatives k, positives j. Block-reduce -> per-block partials.
__global__ __launch_bounds__(256) void triplet_main(
    const float* __restrict__ X,
    const int* __restrict__ labels,
    const float* __restrict__ bias,
    float* __restrict__ psum,
    unsigned* __restrict__ pcnt)
{
    __shared__ float4  xi4[DIM / 4];
    __shared__ float   drow[NPTS];
    __shared__ int     lab[NPTS];
    __shared__ int     poslist[NPTS];
    __shared__ int     npos;
    __shared__ float   wsum[4];
    __shared__ unsigned wcnt[4];

    const int i = blockIdx.x;
    const int t = threadIdx.x;

    for (int j = t; j < NPTS; j += 256) lab[j] = labels[j];
    if (t < DIM / 4) xi4[t] = reinterpret_cast<const float4*>(X + (size_t)i * DIM)[t];
    if (t == 0) npos = 0;
    __syncthreads();

    const int li = lab[i];

    // norm_i from LDS copy of x_i
    float ni = 0.f;
#pragma unroll
    for (int c = 0; c < DIM / 4; ++c) {
        float4 w = xi4[c];
        ni += w.x * w.x + w.y * w.y + w.z * w.z + w.w * w.w;
    }

    // distance row + (unordered) positive list
    for (int j = t; j < NPTS; j += 256) {
        const float4* xj = reinterpret_cast<const float4*>(X + (size_t)j * DIM);
        float dot = 0.f, nj = 0.f;
#pragma unroll
        for (int c = 0; c < DIM / 4; ++c) {
            float4 v = xj[c];
            float4 w = xi4[c];
            dot += v.x * w.x + v.y * w.y + v.z * w.z + v.w * w.w;
            nj  += v.x * v.x + v.y * v.y + v.z * v.z + v.w * v.w;
        }
        float draw = ni + nj - 2.f * dot;
        draw = fmaxf(draw, 0.f);
        drow[j] = (draw == 0.f) ? EPSF : (sqrtf(draw + EPSF) + EPSF);
        if (lab[j] == li && j != i) {
            int p = atomicAdd(&npos, 1);
            poslist[p] = j;
        }
    }
    __syncthreads();

    // deterministic order: tiny insertion sort (npos ~ 8)
    if (t == 0) {
        for (int a = 1; a < npos; ++a) {
            int v = poslist[a];
            int b2 = a - 1;
            while (b2 >= 0 && poslist[b2] > v) { poslist[b2 + 1] = poslist[b2]; --b2; }
            poslist[b2 + 1] = v;
        }
    }
    __syncthreads();

    const float b   = bias[0];
    const int   np_ = npos;
    float    lsum = 0.f;
    unsigned lcnt = 0u;
    for (int k = t; k < NPTS; k += 256) {
        if (lab[k] != li) {
            const float dik = drow[k];
            for (int p = 0; p < np_; ++p) {
                float s = drow[poslist[p]] - dik + b;
                if (s > 0.f) {
                    lsum += s;
                    lcnt += (s > EPSF) ? 1u : 0u;
                }
            }
        }
    }

    // wave (64-lane) shuffle reduce, then cross-wave via LDS
#pragma unroll
    for (int off = 32; off > 0; off >>= 1) {
        lsum += __shfl_down(lsum, off);
        lcnt += __shfl_down(lcnt, off);
    }
    const int wave = t >> 6;
    if ((t & 63) == 0) { wsum[wave] = lsum; wcnt[wave] = lcnt; }
    __syncthreads();
    if (t == 0) {
        psum[i] = wsum[0] + wsum[1] + wsum[2] + wsum[3];
        pcnt[i] = wcnt[0] + wcnt[1] + wcnt[2] + wcnt[3];
    }
}

// Deterministic tree reduction of the 512 per-block partials + final divide.
__global__ __launch_bounds__(256) void triplet_finalize(
    const float* __restrict__ psum,
    const unsigned* __restrict__ pcnt,
    float* __restrict__ out)
{
    __shared__ float    ss[256];
    __shared__ unsigned sc[256];
    const int t = threadIdx.x;
    ss[t] = psum[t] + psum[t + 256];
    sc[t] = pcnt[t] + pcnt[t + 256];
    __syncthreads();
    for (int off = 128; off > 0; off >>= 1) {
        if (t < off) { ss[t] += ss[t + off]; sc[t] += sc[t + off]; }
        __syncthreads();
    }
    if (t == 0) out[0] = ss[0] / ((float)sc[0] + 1e-16f);
}

extern "C" void kernel_launch(void* const* d_in, const int* in_sizes, int n_in,
                              void* d_out, int out_size, void* d_ws, size_t ws_size,
                              hipStream_t stream) {
    const float* X      = (const float*)d_in[0];
    const int*   labels = (const int*)d_in[1];
    const float* bias   = (const float*)d_in[2];
    float*       out    = (float*)d_out;

    float*    psum = (float*)d_ws;
    unsigned* pcnt = (unsigned*)((char*)d_ws + NPTS * sizeof(float));

    triplet_main<<<NPTS, 256, 0, stream>>>(X, labels, bias, psum, pcnt);
    triplet_finalize<<<1, 256, 0, stream>>>(psum, pcnt, out);
}

// Round 2
// 19.922 us; speedup vs baseline: 1.5696x; 1.5696x over previous
//
#include <hip/hip_runtime.h>

#define NPTS   512
#define DIM    128
#define EPSF   1e-16f
#define TROWS  128                 // rows per LDS tile
#define NTILES (NPTS / TROWS)      // 4
#define SROW   144                 // padded row stride in floats (576 B; 576/16=36 ≡ 4 mod 8
                                   // -> each 8-lane octet's 16B windows tile all 32 banks)

// One block per anchor i, 512 threads (8 waves), 2 blocks/CU (LDS ~80 KB).
// Phase 1: 4 tiles of 128 rows staged coalesced into LDS; dot+norm computed by
//          4 lanes per j (32 dims each, interleaved float4 cols) + shfl_xor butterfly.
// Phase 2: positive list (same label, j!=i), insertion-sorted for determinism.
// Phase 3: accumulate sum(relu(d_ij - d_ik + b)) and count(s > 1e-16).
__global__ __launch_bounds__(512, 4) void triplet_main(
    const float* __restrict__ X,
    const int* __restrict__ labels,
    const float* __restrict__ bias,
    float* __restrict__ psum,
    unsigned* __restrict__ pcnt)
{
    __shared__ float    tile[TROWS * SROW];   // 73728 B
    __shared__ float4   xi4[DIM / 4];         // 512 B
    __shared__ float    drow[NPTS];           // 2 KB
    __shared__ int      lab[NPTS];            // 2 KB
    __shared__ int      poslist[NPTS];        // 2 KB
    __shared__ int      npos;
    __shared__ float    wsum[8];
    __shared__ unsigned wcnt[8];

    const int i = blockIdx.x;
    const int t = threadIdx.x;

    if (t < NPTS) lab[t] = labels[t];
    if (t < DIM / 4) xi4[t] = reinterpret_cast<const float4*>(X + (size_t)i * DIM)[t];
    if (t == 0) npos = 0;
    __syncthreads();

    const int li = lab[i];
    const int jl = t >> 2;   // 0..127 : local j within tile
    const int ch = t & 3;    // dim chunk (32 dims, interleaved)

    // anchor fragments in registers: cols ch, ch+4, ..., ch+28
    float4 wx[8];
#pragma unroll
    for (int m = 0; m < 8; ++m) wx[m] = xi4[ch + 4 * m];

    // ni via the same 4-lane butterfly (all lanes end with the full norm)
    float nip = 0.f;
#pragma unroll
    for (int m = 0; m < 8; ++m) {
        float4 w = wx[m];
        nip += w.x * w.x + w.y * w.y + w.z * w.z + w.w * w.w;
    }
    nip += __shfl_xor(nip, 1);
    nip += __shfl_xor(nip, 2);
    const float ni = nip;

    for (int p = 0; p < NTILES; ++p) {
        const int jbase = p * TROWS;
        // coalesced stage: 4096 float4, 8 per thread
        for (int g = t; g < TROWS * (DIM / 4); g += 512) {
            const int r = g >> 5, c4 = g & 31;
            float4 v = reinterpret_cast<const float4*>(X + (size_t)(jbase + r) * DIM)[c4];
            *reinterpret_cast<float4*>(&tile[r * SROW + c4 * 4]) = v;
        }
        __syncthreads();

        float dot = 0.f, nj = 0.f;
#pragma unroll
        for (int m = 0; m < 8; ++m) {
            const int c4 = ch + 4 * m;
            float4 v = *reinterpret_cast<const float4*>(&tile[jl * SROW + c4 * 4]);
            float4 w = wx[m];
            dot += v.x * w.x + v.y * w.y + v.z * w.z + v.w * w.w;
            nj  += v.x * v.x + v.y * v.y + v.z * v.z + v.w * v.w;
        }
        dot += __shfl_xor(dot, 1); dot += __shfl_xor(dot, 2);
        nj  += __shfl_xor(nj , 1); nj  += __shfl_xor(nj , 2);

        if (ch == 0) {
            const int j = jbase + jl;
            float draw = fmaxf(ni + nj - 2.f * dot, 0.f);
            drow[j] = (draw == 0.f) ? EPSF : (sqrtf(draw + EPSF) + EPSF);
            if (lab[j] == li && j != i) {
                int q = atomicAdd(&npos, 1);
                poslist[q] = j;
            }
        }
        __syncthreads();   // tile consumed; safe to restage
    }

    // deterministic order: tiny insertion sort (npos ~ 8 for this data)
    if (t == 0) {
        for (int a = 1; a < npos; ++a) {
            int v = poslist[a];
            int b2 = a - 1;
            while (b2 >= 0 && poslist[b2] > v) { poslist[b2 + 1] = poslist[b2]; --b2; }
            poslist[b2 + 1] = v;
        }
    }
    __syncthreads();

    const float b   = bias[0];
    const int   np_ = npos;
    float    lsum = 0.f;
    unsigned lcnt = 0u;
    {
        const int k = t;   // one negative candidate per thread
        if (lab[k] != li) {
            const float dik = drow[k];
            for (int q = 0; q < np_; ++q) {
                float s = drow[poslist[q]] - dik + b;
                if (s > 0.f) {
                    lsum += s;
                    lcnt += (s > EPSF) ? 1u : 0u;
                }
            }
        }
    }

#pragma unroll
    for (int off = 32; off > 0; off >>= 1) {
        lsum += __shfl_down(lsum, off);
        lcnt += __shfl_down(lcnt, off);
    }
    const int wave = t >> 6;
    if ((t & 63) == 0) { wsum[wave] = lsum; wcnt[wave] = lcnt; }
    __syncthreads();
    if (t == 0) {
        float    s = 0.f;
        unsigned c = 0u;
#pragma unroll
        for (int w = 0; w < 8; ++w) { s += wsum[w]; c += wcnt[w]; }
        psum[i] = s;
        pcnt[i] = c;
    }
}

// Deterministic tree reduction of the 512 per-block partials + final divide.
__global__ __launch_bounds__(256) void triplet_finalize(
    const float* __restrict__ psum,
    const unsigned* __restrict__ pcnt,
    float* __restrict__ out)
{
    __shared__ float    ss[256];
    __shared__ unsigned sc[256];
    const int t = threadIdx.x;
    ss[t] = psum[t] + psum[t + 256];
    sc[t] = pcnt[t] + pcnt[t + 256];
    __syncthreads();
    for (int off = 128; off > 0; off >>= 1) {
        if (t < off) { ss[t] += ss[t + off]; sc[t] += sc[t + off]; }
        __syncthreads();
    }
    if (t == 0) out[0] = ss[0] / ((float)sc[0] + 1e-16f);
}

extern "C" void kernel_launch(void* const* d_in, const int* in_sizes, int n_in,
                              void* d_out, int out_size, void* d_ws, size_t ws_size,
                              hipStream_t stream) {
    const float* X      = (const float*)d_in[0];
    const int*   labels = (const int*)d_in[1];
    const float* bias   = (const float*)d_in[2];
    float*       out    = (float*)d_out;

    float*    psum = (float*)d_ws;
    unsigned* pcnt = (unsigned*)((char*)d_ws + NPTS * sizeof(float));

    triplet_main<<<NPTS, 512, 0, stream>>>(X, labels, bias, psum, pcnt);
    triplet_finalize<<<1, 256, 0, stream>>>(psum, pcnt, out);
}